// Round 2
// baseline (725.459 us; speedup 1.0000x reference)
//
#include <hip/hip_runtime.h>
#include <hip/hip_bf16.h>

// Bahdanau attention, MI355X. B=32, S=2048, H=1024, HL=2048.
// d_out: context[32,1,1024] ++ weights[32,1,2048]  (fp32)
//
// R7: kb16 pre-pass REINTRODUCED, but with the LDS chunk-XOR permutation
// BAKED into the global layout (m173 pre-swizzled-source pattern). The score
// GEMM now stages BOTH A and B via global_load_lds_dwordx4 (m97 structure):
// zero cvt / zero reg-staging in the hot loop -> VALU per K-step ~15 vs 16
// MFMA. Register count drops (no A-prefetch, no cvt temps) -> 4 waves/SIMD.
// kb16 is chunked over batches to fit ws_size (kb16_k/gemm pairs serialized).
//
// ws layout: qws 128K | uat 2M | partial 4M | ctxp 2M | kb16 (adaptive, <=128M)

typedef __attribute__((ext_vector_type(8))) short short8;
typedef __attribute__((ext_vector_type(4))) float floatx4;

typedef const __attribute__((address_space(1))) unsigned int gu32;
typedef __attribute__((address_space(3))) unsigned int lu32;

__device__ __forceinline__ unsigned short f2bf(float f) {
    union { float f; unsigned int u; } c; c.f = f;
    unsigned int u = c.u + 0x7fffu + ((c.u >> 16) & 1u);  // RNE
    return (unsigned short)(u >> 16);
}

// two fp32 -> packed bf16 pair (lo in bits 0..15), RNE either way
__device__ __forceinline__ unsigned int f2bf2(float lo, float hi) {
#if __has_builtin(__builtin_amdgcn_cvt_pk_bf16_f32)
    auto r = __builtin_amdgcn_cvt_pk_bf16_f32(lo, hi);
    unsigned int u; __builtin_memcpy(&u, &r, 4);
    return u;
#else
    return (unsigned int)f2bf(lo) | ((unsigned int)f2bf(hi) << 16);
#endif
}

// async global->LDS, 16B per lane; lane i's data lands at ldsbase + i*16.
__device__ __forceinline__ void gld16(const unsigned short* g, unsigned short* l) {
    __builtin_amdgcn_global_load_lds(
        (gu32*)(uintptr_t)g,
        (lu32*)(unsigned int)(uintptr_t)l,
        16, 0, 0);
}

// ---- K1: q[b,h] = sum_d query[b,d]*Wa[d,h] + Wa_b[h] + Ua_b[h] (fp32 exact) ----
__global__ __launch_bounds__(256) void qproj_k(
    const float* __restrict__ query, const float* __restrict__ Wa,
    const float* __restrict__ Wab, const float* __restrict__ Uab,
    float* __restrict__ qws)
{
    __shared__ float qs[2048];
    __shared__ float red[16*64];
    const int tid = threadIdx.x;
    const int b = blockIdx.x, hc = blockIdx.y;
    #pragma unroll
    for (int i = 0; i < 8; i++) qs[tid + 256*i] = query[b*2048 + tid + 256*i];
    __syncthreads();
    const int hq = tid & 15;      // h-quad within 64-h tile
    const int dg = tid >> 4;      // d-group (128 d each)
    const float4* wp = reinterpret_cast<const float4*>(Wa + (size_t)(dg*128)*1024 + hc*64 + hq*4);
    const float* qp = qs + dg*128;
    float4 a0; a0.x = a0.y = a0.z = a0.w = 0.f;
    float4 a1; a1.x = a1.y = a1.z = a1.w = 0.f;
    #pragma unroll 4
    for (int d = 0; d < 128; d += 2) {
        float q0 = qp[d], q1 = qp[d+1];
        float4 w0 = wp[(size_t)d*256];
        float4 w1 = wp[(size_t)(d+1)*256];
        a0.x += q0*w0.x; a0.y += q0*w0.y; a0.z += q0*w0.z; a0.w += q0*w0.w;
        a1.x += q1*w1.x; a1.y += q1*w1.y; a1.z += q1*w1.z; a1.w += q1*w1.w;
    }
    a0.x += a1.x; a0.y += a1.y; a0.z += a1.z; a0.w += a1.w;
    *reinterpret_cast<float4*>(red + dg*64 + hq*4) = a0;
    __syncthreads();
    if (tid < 64) {
        float v = 0.f;
        #pragma unroll
        for (int g = 0; g < 16; g++) v += red[g*64 + tid];
        int hh = hc*64 + tid;
        qws[b*1024 + hh] = v + Wab[hh] + Uab[hh];
    }
}

// ---- K2: Ua^T bf16: uat[h][d] = bf16(Ua[d][h]) ----
__global__ __launch_bounds__(256) void uat_k(const float* __restrict__ Ua,
                                             unsigned short* __restrict__ uat)
{
    __shared__ unsigned short t[64][65];
    const int x = threadIdx.x & 63, yy = threadIdx.x >> 6;
    const int d0 = blockIdx.x*64, h0 = blockIdx.y*64;
    #pragma unroll
    for (int i = 0; i < 16; i++) {
        int y = yy*16 + i;
        t[y][x] = f2bf(Ua[(size_t)(d0+y)*1024 + h0 + x]);
    }
    __syncthreads();
    #pragma unroll
    for (int i = 0; i < 16; i++) {
        int y = yy*16 + i;
        uat[(size_t)(h0+y)*1024 + d0 + x] = t[x][y];
    }
}

// ---- K2b: keys -> bf16 with baked chunk-XOR layout ----
// For each s-row (1024 k = 32 groups of 4 chunks x 8 elems), within each
// 4-chunk group the uint4 at slot j holds chunk (j ^ p), p = (s>>1)&3.
// Then score-GEMM A-staging is a LINEAR gld16 of this buffer and the LDS
// image lands exactly in the proven swizzled frag layout.
// One thread = one 4-chunk group (read 8x float4, write 4x uint4).
__global__ __launch_bounds__(256) void kb16_k(const float* __restrict__ keys,
                                              unsigned short* __restrict__ kb)
{
    const size_t t = (size_t)blockIdx.x*256 + threadIdx.x;
    const size_t rg = t >> 5;            // local row (chunk_batch*2048 range)
    const int g = (int)(t & 31);         // 32-elem group within row
    const int s = (int)(rg & 2047);
    const int p = (s >> 1) & 3;
    const float4* in4 = reinterpret_cast<const float4*>(keys + rg*1024 + g*32);
    uint4* out4 = reinterpret_cast<uint4*>(kb + rg*1024 + g*32);
    float4 v[8];
    #pragma unroll
    for (int q = 0; q < 8; q++) v[q] = in4[q];
    #pragma unroll
    for (int j = 0; j < 4; j++) {
        int jc = j ^ p;
        uint4 w;
        w.x = f2bf2(v[2*jc].x,   v[2*jc].y);
        w.y = f2bf2(v[2*jc].z,   v[2*jc].w);
        w.z = f2bf2(v[2*jc+1].x, v[2*jc+1].y);
        w.w = f2bf2(v[2*jc+1].z, v[2*jc+1].w);
        out4[j] = w;
    }
}

// ---- K3: score GEMM, both operands via global_load_lds (m97 structure) ----
// LDS rows 64B (32 bf16), 16B chunks XOR-swizzled: slot = chunk ^ ((row>>1)&3).
// A: kb16 already stores the permutation -> linear gld16 (2 instrs/K-step).
// B: uat plain [h][d]; permutation applied via per-lane source offset (proven).
// Frag reads (proven, 0 conflicts): aS + row*32 + ((quad^((row>>1)&3))*8).
// Double-buffered, ONE barrier per K-step; prefetch gld16s drain at barrier.
__global__ __launch_bounds__(256) void score_gemm_fast(
    const unsigned short* __restrict__ kb16,  // [nb][2048][1024] bf16 permuted
    const unsigned short* __restrict__ uat,   // [1024][1024] bf16 [h][d]
    const float* __restrict__ qws,            // [32][1024]
    const float* __restrict__ Va,             // [1024]
    float* __restrict__ partial,              // [32][16][2048]
    int b0)                                   // batch offset of this chunk
{
    __shared__ unsigned short aS[2][128*32];  // 16KB
    __shared__ unsigned short bS[2][128*32];  // 16KB
    const int tid = threadIdx.x;
    const int bz = blockIdx.z;                 // local batch
    const int b = b0 + bz;                     // global batch
    const int s0 = blockIdx.x * 128;
    const int h0 = blockIdx.y * 128;
    const int lane = tid & 63, wave = tid >> 6;
    const int quad = lane >> 4, l15 = lane & 15;
    const int wm = (wave & 1) * 64, wn = (wave >> 1) * 64;

    // B-staging source (runtime-permuted, proven)
    const int srow = lane >> 2;
    const int schunk = (lane & 3) ^ ((srow >> 1) & 3);
    const int c0 = wave*2, c1 = wave*2 + 1;
    const unsigned short* ubase = uat + (size_t)h0*1024;
    const size_t boff0 = (size_t)(c0*16 + srow)*1024 + schunk*8;
    const size_t boff1 = (size_t)(c1*16 + srow)*1024 + schunk*8;

    // A-staging source (baked-permuted, linear): instr i covers f = i*256+tid,
    // row = f>>2, slot = f&3; src offset = row*1024 + k0 + slot*8.
    const unsigned short* kA = kb16 + (size_t)(bz*2048 + s0)*1024;
    const size_t aoff0 = (size_t)(tid >> 2)*1024 + (size_t)(tid & 3)*8;
    const size_t aoff1 = (size_t)(64 + (tid >> 2))*1024 + (size_t)(tid & 3)*8;

    floatx4 acc[4][4];
    #pragma unroll
    for (int i = 0; i < 4; i++)
        #pragma unroll
        for (int j = 0; j < 4; j++) acc[i][j] = (floatx4)0.0f;

    // ---- prologue: stage tile 0 into buffer 0 ----
    gld16(kA + aoff0,    aS[0] + wave*512);
    gld16(kA + aoff1,    aS[0] + 2048 + wave*512);
    gld16(ubase + boff0, bS[0] + c0*512);
    gld16(ubase + boff1, bS[0] + c1*512);
    __syncthreads();

    int cur = 0;
    for (int kt = 0; kt < 31; ++kt) {
        const int nxt = cur ^ 1;
        const int k1 = (kt + 1) << 5;

        // prefetch tile kt+1 into idle buffer (4 async instrs, no VGPR traffic)
        gld16(kA + aoff0 + k1,    aS[nxt] + wave*512);
        gld16(kA + aoff1 + k1,    aS[nxt] + 2048 + wave*512);
        gld16(ubase + boff0 + k1, bS[nxt] + c0*512);
        gld16(ubase + boff1 + k1, bS[nxt] + c1*512);

        // compute tile kt from buf cur
        short8 af[4], bf8[4];
        #pragma unroll
        for (int i = 0; i < 4; i++) {
            int row = wm + 16*i + l15;
            af[i] = *reinterpret_cast<const short8*>(aS[cur] + row*32 + ((quad ^ ((row>>1)&3)) * 8));
        }
        #pragma unroll
        for (int j = 0; j < 4; j++) {
            int row = wn + 16*j + l15;
            bf8[j] = *reinterpret_cast<const short8*>(bS[cur] + row*32 + ((quad ^ ((row>>1)&3)) * 8));
        }
        #pragma unroll
        for (int i = 0; i < 4; i++)
            #pragma unroll
            for (int j = 0; j < 4; j++)
                acc[i][j] = __builtin_amdgcn_mfma_f32_16x16x32_bf16(af[i], bf8[j], acc[i][j], 0, 0, 0);

        __syncthreads();   // drains prefetch vmcnt + frag lgkm; one barrier/K-step
        cur = nxt;
    }

    // ---- last tile: compute only ----
    {
        short8 af[4], bf8[4];
        #pragma unroll
        for (int i = 0; i < 4; i++) {
            int row = wm + 16*i + l15;
            af[i] = *reinterpret_cast<const short8*>(aS[cur] + row*32 + ((quad ^ ((row>>1)&3)) * 8));
        }
        #pragma unroll
        for (int j = 0; j < 4; j++) {
            int row = wn + 16*j + l15;
            bf8[j] = *reinterpret_cast<const short8*>(bS[cur] + row*32 + ((quad ^ ((row>>1)&3)) * 8));
        }
        #pragma unroll
        for (int i = 0; i < 4; i++)
            #pragma unroll
            for (int j = 0; j < 4; j++)
                acc[i][j] = __builtin_amdgcn_mfma_f32_16x16x32_bf16(af[i], bf8[j], acc[i][j], 0, 0, 0);
    }

    // epilogue: p[s] = sum_n Va[n]*tanh(q[n]+k[s,n]); C-layout: n=lane&15, m=quad*4+reg
    float qv[4], vav[4];
    #pragma unroll
    for (int j = 0; j < 4; j++) {
        int n = h0 + wn + 16*j + l15;
        qv[j]  = qws[b*1024 + n];
        vav[j] = Va[n];
    }
    const int slot = blockIdx.y * 2 + (wave >> 1);   // unique per (h-tile, n-half)
    #pragma unroll
    for (int i = 0; i < 4; i++) {
        #pragma unroll
        for (int r = 0; r < 4; r++) {
            float p = 0.f;
            #pragma unroll
            for (int j = 0; j < 4; j++) {
                float x = qv[j] + acc[i][j][r];
                float e = __expf(2.f * x);                       // tanh = 1 - 2/(e^{2x}+1)
                float t = 1.f - 2.f * __builtin_amdgcn_rcpf(e + 1.f);
                p += vav[j] * t;
            }
            #pragma unroll
            for (int off = 1; off < 16; off <<= 1) p += __shfl_xor(p, off, 64);
            if (l15 == 0) {
                int m = wm + 16*i + quad*4 + r;
                partial[((size_t)b*16 + slot)*2048 + s0 + m] = p;
            }
        }
    }
}

// ---- K4: softmax over s per batch ----
__global__ __launch_bounds__(256) void softmax_k(const float* __restrict__ partial,
                                                 float* __restrict__ out_w)
{
    const int tid = threadIdx.x;
    const int b = blockIdx.x;
    __shared__ float wred[4], wred2[4];
    float sc[8];
    float mx = -3.0e38f;
    #pragma unroll
    for (int i = 0; i < 8; i++) {
        int s = tid + 256*i;
        float v = 0.f;
        #pragma unroll
        for (int ht = 0; ht < 16; ht++) v += partial[((size_t)b*16 + ht)*2048 + s];
        sc[i] = v; mx = fmaxf(mx, v);
    }
    #pragma unroll
    for (int off = 32; off >= 1; off >>= 1) mx = fmaxf(mx, __shfl_xor(mx, off, 64));
    if ((tid & 63) == 0) wred[tid >> 6] = mx;
    __syncthreads();
    mx = fmaxf(fmaxf(wred[0], wred[1]), fmaxf(wred[2], wred[3]));
    float e[8]; float lsum = 0.f;
    #pragma unroll
    for (int i = 0; i < 8; i++) { e[i] = __expf(sc[i] - mx); lsum += e[i]; }
    #pragma unroll
    for (int off = 32; off >= 1; off >>= 1) lsum += __shfl_xor(lsum, off, 64);
    if ((tid & 63) == 0) wred2[tid >> 6] = lsum;
    __syncthreads();
    float inv = 1.0f / (wred2[0] + wred2[1] + wred2[2] + wred2[3]);
    #pragma unroll
    for (int i = 0; i < 8; i++) out_w[b*2048 + tid + 256*i] = e[i] * inv;
}

// ---- K5: context partials over s-chunks ----
__global__ __launch_bounds__(256) void ctx_k(const float* __restrict__ keys,
                                             const float* __restrict__ w,
                                             float* __restrict__ ctxp, int sper)
{
    const int tid = threadIdx.x;
    const int b = blockIdx.x, sc = blockIdx.y;
    const float4* k4 = reinterpret_cast<const float4*>(keys) + (size_t)(b*2048 + sc*sper)*256;
    const float* wp = w + b*2048 + sc*sper;
    float4 a; a.x = a.y = a.z = a.w = 0.f;
    #pragma unroll 4
    for (int s = 0; s < sper; s++) {
        float wv = wp[s];
        float4 kv = k4[(size_t)s*256 + tid];
        a.x += wv*kv.x; a.y += wv*kv.y; a.z += wv*kv.z; a.w += wv*kv.w;
    }
    reinterpret_cast<float4*>(ctxp)[((size_t)b*gridDim.y + sc)*256 + tid] = a;
}

// ---- K6: reduce context partials ----
__global__ __launch_bounds__(256) void ctxsum_k(const float* __restrict__ ctxp,
                                                float* __restrict__ out, int nc)
{
    const int idx = blockIdx.x*256 + threadIdx.x;   // b*1024 + h
    const int b = idx >> 10, h = idx & 1023;
    float v = 0.f;
    for (int s = 0; s < nc; s++) v += ctxp[((size_t)b*nc + s)*1024 + h];
    out[idx] = v;
}

extern "C" void kernel_launch(void* const* d_in, const int* in_sizes, int n_in,
                              void* d_out, int out_size, void* d_ws, size_t ws_size,
                              hipStream_t stream)
{
    const float* query = (const float*)d_in[0];
    const float* keys  = (const float*)d_in[1];
    const float* Wa_w  = (const float*)d_in[2];
    const float* Wa_b  = (const float*)d_in[3];
    const float* Ua_w  = (const float*)d_in[4];
    const float* Ua_b  = (const float*)d_in[5];
    const float* Va_w  = (const float*)d_in[6];
    // d_in[7] (Va_b) is a uniform shift on scores -> softmax-invariant; unused.

    char* ws = (char*)d_ws;
    float*          qws     = (float*)(ws);                       // 128 KiB
    unsigned short* uat     = (unsigned short*)(ws + (131072));   // 2 MiB
    float*          partial = (float*)(ws + (131072 + 2097152));  // 4 MiB
    float*          ctxp    = (float*)(ws + (131072 + 2097152 + 4194304)); // 2 MiB
    const size_t BASE = 131072 + 2097152 + 4194304 + 2097152;     // 8.52 MiB
    unsigned short* kb16 = (unsigned short*)(ws + BASE);

    // pick largest batch-chunk whose kb16 fits the remaining workspace
    size_t avail = (ws_size > BASE) ? (ws_size - BASE) : 0;
    int nb = 32;
    while (nb > 1 && (size_t)nb * 2048 * 1024 * 2 > avail) nb >>= 1;

    float* out_ctx = (float*)d_out;          // [32*1024]
    float* out_w   = out_ctx + 32*1024;      // [32*2048]

    qproj_k<<<dim3(32, 16), 256, 0, stream>>>(query, Wa_w, Wa_b, Ua_b, qws);
    uat_k  <<<dim3(16, 16), 256, 0, stream>>>(Ua_w, uat);
    for (int b0 = 0; b0 < 32; b0 += nb) {
        kb16_k<<<dim3(nb*256), 256, 0, stream>>>(keys + (size_t)b0*2048*1024, kb16);
        score_gemm_fast<<<dim3(16, 8, nb), 256, 0, stream>>>(kb16, uat, qws, Va_w, partial, b0);
    }
    softmax_k<<<dim3(32),      256, 0, stream>>>(partial, out_w);
    ctx_k    <<<dim3(32, 16),  256, 0, stream>>>(keys, out_w, ctxp, 128);
    ctxsum_k <<<dim3(128),     256, 0, stream>>>(ctxp, out_ctx, 16);
}

// Round 3
// 647.357 us; speedup vs baseline: 1.1206x; 1.1206x over previous
//
#include <hip/hip_runtime.h>
#include <hip/hip_bf16.h>

// Bahdanau attention, MI355X. B=32, S=2048, H=1024, HL=2048.
// d_out: context[32,1,1024] ++ weights[32,1,2048]  (fp32)
//
// R8: kb16_k rewritten fully coalesced (float4/lane reads, uint2 writes with
// chunk-XOR baked into the DEST slot; layout bit-identical to R7's).  Score
// GEMM epilogue now atomicAdds into score[32][2048] (replaces 16-slot partial
// buffer) so softmax is a single-pass read.  score buffer memset per launch.
//
// ws layout: qws 128K | uat 2M | score 256K(+pad 4M region) | ctxp 2M | kb16

typedef __attribute__((ext_vector_type(8))) short short8;
typedef __attribute__((ext_vector_type(4))) float floatx4;

typedef const __attribute__((address_space(1))) unsigned int gu32;
typedef __attribute__((address_space(3))) unsigned int lu32;

__device__ __forceinline__ unsigned short f2bf(float f) {
    union { float f; unsigned int u; } c; c.f = f;
    unsigned int u = c.u + 0x7fffu + ((c.u >> 16) & 1u);  // RNE
    return (unsigned short)(u >> 16);
}

// two fp32 -> packed bf16 pair (lo in bits 0..15), RNE either way
__device__ __forceinline__ unsigned int f2bf2(float lo, float hi) {
#if __has_builtin(__builtin_amdgcn_cvt_pk_bf16_f32)
    auto r = __builtin_amdgcn_cvt_pk_bf16_f32(lo, hi);
    unsigned int u; __builtin_memcpy(&u, &r, 4);
    return u;
#else
    return (unsigned int)f2bf(lo) | ((unsigned int)f2bf(hi) << 16);
#endif
}

// async global->LDS, 16B per lane; lane i's data lands at ldsbase + i*16.
__device__ __forceinline__ void gld16(const unsigned short* g, unsigned short* l) {
    __builtin_amdgcn_global_load_lds(
        (gu32*)(uintptr_t)g,
        (lu32*)(unsigned int)(uintptr_t)l,
        16, 0, 0);
}

// ---- K1: q[b,h] = sum_d query[b,d]*Wa[d,h] + Wa_b[h] + Ua_b[h] (fp32 exact) ----
__global__ __launch_bounds__(256) void qproj_k(
    const float* __restrict__ query, const float* __restrict__ Wa,
    const float* __restrict__ Wab, const float* __restrict__ Uab,
    float* __restrict__ qws)
{
    __shared__ float qs[2048];
    __shared__ float red[16*64];
    const int tid = threadIdx.x;
    const int b = blockIdx.x, hc = blockIdx.y;
    #pragma unroll
    for (int i = 0; i < 8; i++) qs[tid + 256*i] = query[b*2048 + tid + 256*i];
    __syncthreads();
    const int hq = tid & 15;      // h-quad within 64-h tile
    const int dg = tid >> 4;      // d-group (128 d each)
    const float4* wp = reinterpret_cast<const float4*>(Wa + (size_t)(dg*128)*1024 + hc*64 + hq*4);
    const float* qp = qs + dg*128;
    float4 a0; a0.x = a0.y = a0.z = a0.w = 0.f;
    float4 a1; a1.x = a1.y = a1.z = a1.w = 0.f;
    #pragma unroll 4
    for (int d = 0; d < 128; d += 2) {
        float q0 = qp[d], q1 = qp[d+1];
        float4 w0 = wp[(size_t)d*256];
        float4 w1 = wp[(size_t)(d+1)*256];
        a0.x += q0*w0.x; a0.y += q0*w0.y; a0.z += q0*w0.z; a0.w += q0*w0.w;
        a1.x += q1*w1.x; a1.y += q1*w1.y; a1.z += q1*w1.z; a1.w += q1*w1.w;
    }
    a0.x += a1.x; a0.y += a1.y; a0.z += a1.z; a0.w += a1.w;
    *reinterpret_cast<float4*>(red + dg*64 + hq*4) = a0;
    __syncthreads();
    if (tid < 64) {
        float v = 0.f;
        #pragma unroll
        for (int g = 0; g < 16; g++) v += red[g*64 + tid];
        int hh = hc*64 + tid;
        qws[b*1024 + hh] = v + Wab[hh] + Uab[hh];
    }
}

// ---- K2: Ua^T bf16: uat[h][d] = bf16(Ua[d][h]) ----
__global__ __launch_bounds__(256) void uat_k(const float* __restrict__ Ua,
                                             unsigned short* __restrict__ uat)
{
    __shared__ unsigned short t[64][65];
    const int x = threadIdx.x & 63, yy = threadIdx.x >> 6;
    const int d0 = blockIdx.x*64, h0 = blockIdx.y*64;
    #pragma unroll
    for (int i = 0; i < 16; i++) {
        int y = yy*16 + i;
        t[y][x] = f2bf(Ua[(size_t)(d0+y)*1024 + h0 + x]);
    }
    __syncthreads();
    #pragma unroll
    for (int i = 0; i < 16; i++) {
        int y = yy*16 + i;
        uat[(size_t)(h0+y)*1024 + d0 + x] = t[x][y];
    }
}

// ---- K2b: keys -> bf16 with baked chunk-XOR layout (coalesced) ----
// Layout identical to R7 kb16: within each 32-elem group of row s, the 16B
// slot j holds source chunk (j ^ p), p = (s>>1)&3.  Here each lane converts
// ONE float4 (16B read, perfectly lane-consecutive) and writes one uint2 (8B)
// to dest slot (c^p): writes are permuted only inside 64B windows.
// Grid-stride x4 for ILP. nf4 = total float4 count for this chunk.
__global__ __launch_bounds__(256) void kb16_k(const float* __restrict__ keys,
                                              unsigned short* __restrict__ kb,
                                              unsigned int nf4)
{
    const unsigned int stride = gridDim.x * 256u;
    unsigned int f = blockIdx.x * 256u + threadIdx.x;
    #pragma unroll 4
    for (int it = 0; it < 4; ++it, f += stride) {
        if (f < nf4) {
            unsigned int elem = f << 2;                 // source element offset
            unsigned int rg   = elem >> 10;             // row
            unsigned int rem  = elem & 1023u;
            unsigned int g    = rem >> 5;               // 32-elem group
            unsigned int c    = (rem >> 3) & 3u;        // source chunk in group
            unsigned int half = (rem >> 2) & 1u;        // float4 within chunk
            unsigned int p    = ((rg & 2047u) >> 1) & 3u;
            float4 v = reinterpret_cast<const float4*>(keys)[f];
            uint2 w;
            w.x = f2bf2(v.x, v.y);
            w.y = f2bf2(v.z, v.w);
            unsigned int dst = rg*1024u + g*32u + ((c ^ p) << 3) + (half << 2);
            *reinterpret_cast<uint2*>(kb + dst) = w;
        }
    }
}

// ---- K3: score GEMM, both operands via global_load_lds (m97 structure) ----
// LDS rows 64B (32 bf16), 16B chunks XOR-swizzled: slot = chunk ^ ((row>>1)&3).
// A: kb16 already stores the permutation -> linear gld16 (2 instrs/K-step).
// B: uat plain [h][d]; permutation applied via per-lane source offset (proven).
// Frag reads (proven, 0 conflicts): aS + row*32 + ((quad^((row>>1)&3))*8).
// Double-buffered, ONE barrier per K-step; prefetch gld16s drain at barrier.
// Epilogue: atomicAdd h-tile partial scores into score[32][2048].
__global__ __launch_bounds__(256) void score_gemm_fast(
    const unsigned short* __restrict__ kb16,  // [nb][2048][1024] bf16 permuted
    const unsigned short* __restrict__ uat,   // [1024][1024] bf16 [h][d]
    const float* __restrict__ qws,            // [32][1024]
    const float* __restrict__ Va,             // [1024]
    float* __restrict__ score,                // [32][2048] (pre-zeroed)
    int b0)                                   // batch offset of this chunk
{
    __shared__ unsigned short aS[2][128*32];  // 16KB
    __shared__ unsigned short bS[2][128*32];  // 16KB
    const int tid = threadIdx.x;
    const int bz = blockIdx.z;                 // local batch
    const int b = b0 + bz;                     // global batch
    const int s0 = blockIdx.x * 128;
    const int h0 = blockIdx.y * 128;
    const int lane = tid & 63, wave = tid >> 6;
    const int quad = lane >> 4, l15 = lane & 15;
    const int wm = (wave & 1) * 64, wn = (wave >> 1) * 64;

    // B-staging source (runtime-permuted, proven)
    const int srow = lane >> 2;
    const int schunk = (lane & 3) ^ ((srow >> 1) & 3);
    const int c0 = wave*2, c1 = wave*2 + 1;
    const unsigned short* ubase = uat + (size_t)h0*1024;
    const size_t boff0 = (size_t)(c0*16 + srow)*1024 + schunk*8;
    const size_t boff1 = (size_t)(c1*16 + srow)*1024 + schunk*8;

    // A-staging source (baked-permuted, linear)
    const unsigned short* kA = kb16 + (size_t)(bz*2048 + s0)*1024;
    const size_t aoff0 = (size_t)(tid >> 2)*1024 + (size_t)(tid & 3)*8;
    const size_t aoff1 = (size_t)(64 + (tid >> 2))*1024 + (size_t)(tid & 3)*8;

    floatx4 acc[4][4];
    #pragma unroll
    for (int i = 0; i < 4; i++)
        #pragma unroll
        for (int j = 0; j < 4; j++) acc[i][j] = (floatx4)0.0f;

    // ---- prologue: stage tile 0 into buffer 0 ----
    gld16(kA + aoff0,    aS[0] + wave*512);
    gld16(kA + aoff1,    aS[0] + 2048 + wave*512);
    gld16(ubase + boff0, bS[0] + c0*512);
    gld16(ubase + boff1, bS[0] + c1*512);
    __syncthreads();

    int cur = 0;
    for (int kt = 0; kt < 31; ++kt) {
        const int nxt = cur ^ 1;
        const int k1 = (kt + 1) << 5;

        // prefetch tile kt+1 into idle buffer (4 async instrs, no VGPR traffic)
        gld16(kA + aoff0 + k1,    aS[nxt] + wave*512);
        gld16(kA + aoff1 + k1,    aS[nxt] + 2048 + wave*512);
        gld16(ubase + boff0 + k1, bS[nxt] + c0*512);
        gld16(ubase + boff1 + k1, bS[nxt] + c1*512);

        // compute tile kt from buf cur
        short8 af[4], bf8[4];
        #pragma unroll
        for (int i = 0; i < 4; i++) {
            int row = wm + 16*i + l15;
            af[i] = *reinterpret_cast<const short8*>(aS[cur] + row*32 + ((quad ^ ((row>>1)&3)) * 8));
        }
        #pragma unroll
        for (int j = 0; j < 4; j++) {
            int row = wn + 16*j + l15;
            bf8[j] = *reinterpret_cast<const short8*>(bS[cur] + row*32 + ((quad ^ ((row>>1)&3)) * 8));
        }
        #pragma unroll
        for (int i = 0; i < 4; i++)
            #pragma unroll
            for (int j = 0; j < 4; j++)
                acc[i][j] = __builtin_amdgcn_mfma_f32_16x16x32_bf16(af[i], bf8[j], acc[i][j], 0, 0, 0);

        __syncthreads();   // drains prefetch vmcnt + frag lgkm; one barrier/K-step
        cur = nxt;
    }

    // ---- last tile: compute only ----
    {
        short8 af[4], bf8[4];
        #pragma unroll
        for (int i = 0; i < 4; i++) {
            int row = wm + 16*i + l15;
            af[i] = *reinterpret_cast<const short8*>(aS[cur] + row*32 + ((quad ^ ((row>>1)&3)) * 8));
        }
        #pragma unroll
        for (int j = 0; j < 4; j++) {
            int row = wn + 16*j + l15;
            bf8[j] = *reinterpret_cast<const short8*>(bS[cur] + row*32 + ((quad ^ ((row>>1)&3)) * 8));
        }
        #pragma unroll
        for (int i = 0; i < 4; i++)
            #pragma unroll
            for (int j = 0; j < 4; j++)
                acc[i][j] = __builtin_amdgcn_mfma_f32_16x16x32_bf16(af[i], bf8[j], acc[i][j], 0, 0, 0);
    }

    // epilogue: p[s] = sum_n Va[n]*tanh(q[n]+k[s,n]); C-layout: n=lane&15, m=quad*4+reg
    float qv[4], vav[4];
    #pragma unroll
    for (int j = 0; j < 4; j++) {
        int n = h0 + wn + 16*j + l15;
        qv[j]  = qws[b*1024 + n];
        vav[j] = Va[n];
    }
    #pragma unroll
    for (int i = 0; i < 4; i++) {
        #pragma unroll
        for (int r = 0; r < 4; r++) {
            float p = 0.f;
            #pragma unroll
            for (int j = 0; j < 4; j++) {
                float x = qv[j] + acc[i][j][r];
                float e = __expf(2.f * x);                       // tanh = 1 - 2/(e^{2x}+1)
                float t = 1.f - 2.f * __builtin_amdgcn_rcpf(e + 1.f);
                p += vav[j] * t;
            }
            #pragma unroll
            for (int off = 1; off < 16; off <<= 1) p += __shfl_xor(p, off, 64);
            if (l15 == 0) {
                int m = wm + 16*i + quad*4 + r;
                atomicAdd(score + (size_t)b*2048 + s0 + m, p);
            }
        }
    }
}

// ---- K4: softmax over s per batch (single-pass; score pre-reduced) ----
__global__ __launch_bounds__(256) void softmax_k(const float* __restrict__ score,
                                                 float* __restrict__ out_w)
{
    const int tid = threadIdx.x;
    const int b = blockIdx.x;
    __shared__ float wred[4], wred2[4];
    float sc[8];
    float mx = -3.0e38f;
    #pragma unroll
    for (int i = 0; i < 8; i++) {
        sc[i] = score[(size_t)b*2048 + tid + 256*i];
        mx = fmaxf(mx, sc[i]);
    }
    #pragma unroll
    for (int off = 32; off >= 1; off >>= 1) mx = fmaxf(mx, __shfl_xor(mx, off, 64));
    if ((tid & 63) == 0) wred[tid >> 6] = mx;
    __syncthreads();
    mx = fmaxf(fmaxf(wred[0], wred[1]), fmaxf(wred[2], wred[3]));
    float e[8]; float lsum = 0.f;
    #pragma unroll
    for (int i = 0; i < 8; i++) { e[i] = __expf(sc[i] - mx); lsum += e[i]; }
    #pragma unroll
    for (int off = 32; off >= 1; off >>= 1) lsum += __shfl_xor(lsum, off, 64);
    if ((tid & 63) == 0) wred2[tid >> 6] = lsum;
    __syncthreads();
    float inv = 1.0f / (wred2[0] + wred2[1] + wred2[2] + wred2[3]);
    #pragma unroll
    for (int i = 0; i < 8; i++) out_w[b*2048 + tid + 256*i] = e[i] * inv;
}

// ---- K5: context partials over s-chunks ----
__global__ __launch_bounds__(256) void ctx_k(const float* __restrict__ keys,
                                             const float* __restrict__ w,
                                             float* __restrict__ ctxp, int sper)
{
    const int tid = threadIdx.x;
    const int b = blockIdx.x, sc = blockIdx.y;
    const float4* k4 = reinterpret_cast<const float4*>(keys) + (size_t)(b*2048 + sc*sper)*256;
    const float* wp = w + b*2048 + sc*sper;
    float4 a; a.x = a.y = a.z = a.w = 0.f;
    #pragma unroll 4
    for (int s = 0; s < sper; s++) {
        float wv = wp[s];
        float4 kv = k4[(size_t)s*256 + tid];
        a.x += wv*kv.x; a.y += wv*kv.y; a.z += wv*kv.z; a.w += wv*kv.w;
    }
    reinterpret_cast<float4*>(ctxp)[((size_t)b*gridDim.y + sc)*256 + tid] = a;
}

// ---- K6: reduce context partials ----
__global__ __launch_bounds__(256) void ctxsum_k(const float* __restrict__ ctxp,
                                                float* __restrict__ out, int nc)
{
    const int idx = blockIdx.x*256 + threadIdx.x;   // b*1024 + h
    const int b = idx >> 10, h = idx & 1023;
    float v = 0.f;
    for (int s = 0; s < nc; s++) v += ctxp[((size_t)b*nc + s)*1024 + h];
    out[idx] = v;
}

extern "C" void kernel_launch(void* const* d_in, const int* in_sizes, int n_in,
                              void* d_out, int out_size, void* d_ws, size_t ws_size,
                              hipStream_t stream)
{
    const float* query = (const float*)d_in[0];
    const float* keys  = (const float*)d_in[1];
    const float* Wa_w  = (const float*)d_in[2];
    const float* Wa_b  = (const float*)d_in[3];
    const float* Ua_w  = (const float*)d_in[4];
    const float* Ua_b  = (const float*)d_in[5];
    const float* Va_w  = (const float*)d_in[6];
    // d_in[7] (Va_b) is a uniform shift on scores -> softmax-invariant; unused.

    char* ws = (char*)d_ws;
    float*          qws     = (float*)(ws);                       // 128 KiB
    unsigned short* uat     = (unsigned short*)(ws + (131072));   // 2 MiB
    float*          score   = (float*)(ws + (131072 + 2097152));  // 256 KiB (4M region)
    float*          ctxp    = (float*)(ws + (131072 + 2097152 + 4194304)); // 2 MiB
    const size_t BASE = 131072 + 2097152 + 4194304 + 2097152;     // 8.52 MiB
    unsigned short* kb16 = (unsigned short*)(ws + BASE);

    // pick largest batch-chunk whose kb16 fits the remaining workspace
    size_t avail = (ws_size > BASE) ? (ws_size - BASE) : 0;
    int nb = 32;
    while (nb > 1 && (size_t)nb * 2048 * 1024 * 2 > avail) nb >>= 1;

    float* out_ctx = (float*)d_out;          // [32*1024]
    float* out_w   = out_ctx + 32*1024;      // [32*2048]

    hipMemsetAsync(score, 0, 32*2048*sizeof(float), stream);
    qproj_k<<<dim3(32, 16), 256, 0, stream>>>(query, Wa_w, Wa_b, Ua_b, qws);
    uat_k  <<<dim3(16, 16), 256, 0, stream>>>(Ua_w, uat);
    for (int b0 = 0; b0 < 32; b0 += nb) {
        unsigned int nf4 = (unsigned int)nb * 2048u * 256u;
        unsigned int nthr = (nf4 + 3u) / 4u;
        unsigned int nblk = (nthr + 255u) / 256u;
        kb16_k<<<dim3(nblk), 256, 0, stream>>>(keys + (size_t)b0*2048*1024, kb16, nf4);
        score_gemm_fast<<<dim3(16, 8, nb), 256, 0, stream>>>(kb16, uat, qws, Va_w, score, b0);
    }
    softmax_k<<<dim3(32),      256, 0, stream>>>(score, out_w);
    ctx_k    <<<dim3(32, 16),  256, 0, stream>>>(keys, out_w, ctxp, 128);
    ctxsum_k <<<dim3(128),     256, 0, stream>>>(ctxp, out_ctx, 16);
}

// Round 4
// 622.367 us; speedup vs baseline: 1.1656x; 1.0402x over previous
//
#include <hip/hip_runtime.h>
#include <hip/hip_bf16.h>

// Bahdanau attention, MI355X. B=32, S=2048, H=1024, HL=2048.
// d_out: context[32,1,1024] ++ weights[32,1,2048]  (fp32)
//
// R9: score GEMM N-tile widened 128->256 (parameter change on the proven
// template): per K-step 32 MFMA vs same staging overhead -> predicted
// MfmaUtil ~45%. B staging 4x gld16, bf8[8], acc[4][8], grid y=4.
// ctx_k now atomicAdds into out_ctx directly; ctxsum_k + ctxp deleted.
//
// ws layout: qws 128K | uat 2M | score 256K(4M region) | (2M spare) | kb16

typedef __attribute__((ext_vector_type(8))) short short8;
typedef __attribute__((ext_vector_type(4))) float floatx4;

typedef const __attribute__((address_space(1))) unsigned int gu32;
typedef __attribute__((address_space(3))) unsigned int lu32;

__device__ __forceinline__ unsigned short f2bf(float f) {
    union { float f; unsigned int u; } c; c.f = f;
    unsigned int u = c.u + 0x7fffu + ((c.u >> 16) & 1u);  // RNE
    return (unsigned short)(u >> 16);
}

// two fp32 -> packed bf16 pair (lo in bits 0..15), RNE either way
__device__ __forceinline__ unsigned int f2bf2(float lo, float hi) {
#if __has_builtin(__builtin_amdgcn_cvt_pk_bf16_f32)
    auto r = __builtin_amdgcn_cvt_pk_bf16_f32(lo, hi);
    unsigned int u; __builtin_memcpy(&u, &r, 4);
    return u;
#else
    return (unsigned int)f2bf(lo) | ((unsigned int)f2bf(hi) << 16);
#endif
}

// async global->LDS, 16B per lane; lane i's data lands at ldsbase + i*16.
__device__ __forceinline__ void gld16(const unsigned short* g, unsigned short* l) {
    __builtin_amdgcn_global_load_lds(
        (gu32*)(uintptr_t)g,
        (lu32*)(unsigned int)(uintptr_t)l,
        16, 0, 0);
}

// ---- K1: q[b,h] = sum_d query[b,d]*Wa[d,h] + Wa_b[h] + Ua_b[h] (fp32 exact) ----
__global__ __launch_bounds__(256) void qproj_k(
    const float* __restrict__ query, const float* __restrict__ Wa,
    const float* __restrict__ Wab, const float* __restrict__ Uab,
    float* __restrict__ qws)
{
    __shared__ float qs[2048];
    __shared__ float red[16*64];
    const int tid = threadIdx.x;
    const int b = blockIdx.x, hc = blockIdx.y;
    #pragma unroll
    for (int i = 0; i < 8; i++) qs[tid + 256*i] = query[b*2048 + tid + 256*i];
    __syncthreads();
    const int hq = tid & 15;      // h-quad within 64-h tile
    const int dg = tid >> 4;      // d-group (128 d each)
    const float4* wp = reinterpret_cast<const float4*>(Wa + (size_t)(dg*128)*1024 + hc*64 + hq*4);
    const float* qp = qs + dg*128;
    float4 a0; a0.x = a0.y = a0.z = a0.w = 0.f;
    float4 a1; a1.x = a1.y = a1.z = a1.w = 0.f;
    #pragma unroll 4
    for (int d = 0; d < 128; d += 2) {
        float q0 = qp[d], q1 = qp[d+1];
        float4 w0 = wp[(size_t)d*256];
        float4 w1 = wp[(size_t)(d+1)*256];
        a0.x += q0*w0.x; a0.y += q0*w0.y; a0.z += q0*w0.z; a0.w += q0*w0.w;
        a1.x += q1*w1.x; a1.y += q1*w1.y; a1.z += q1*w1.z; a1.w += q1*w1.w;
    }
    a0.x += a1.x; a0.y += a1.y; a0.z += a1.z; a0.w += a1.w;
    *reinterpret_cast<float4*>(red + dg*64 + hq*4) = a0;
    __syncthreads();
    if (tid < 64) {
        float v = 0.f;
        #pragma unroll
        for (int g = 0; g < 16; g++) v += red[g*64 + tid];
        int hh = hc*64 + tid;
        qws[b*1024 + hh] = v + Wab[hh] + Uab[hh];
    }
}

// ---- K2: Ua^T bf16: uat[h][d] = bf16(Ua[d][h]) ----
__global__ __launch_bounds__(256) void uat_k(const float* __restrict__ Ua,
                                             unsigned short* __restrict__ uat)
{
    __shared__ unsigned short t[64][65];
    const int x = threadIdx.x & 63, yy = threadIdx.x >> 6;
    const int d0 = blockIdx.x*64, h0 = blockIdx.y*64;
    #pragma unroll
    for (int i = 0; i < 16; i++) {
        int y = yy*16 + i;
        t[y][x] = f2bf(Ua[(size_t)(d0+y)*1024 + h0 + x]);
    }
    __syncthreads();
    #pragma unroll
    for (int i = 0; i < 16; i++) {
        int y = yy*16 + i;
        uat[(size_t)(h0+y)*1024 + d0 + x] = t[x][y];
    }
}

// ---- K2b: keys -> bf16 with baked chunk-XOR layout (coalesced) ----
// Within each 32-elem group of row s, the 16B slot j holds source chunk
// (j ^ p), p = (s>>1)&3.  Each lane converts ONE float4 (16B coalesced read)
// and writes one uint2 (8B) to dest slot (c^p): permuted only inside 64B.
__global__ __launch_bounds__(256) void kb16_k(const float* __restrict__ keys,
                                              unsigned short* __restrict__ kb,
                                              unsigned int nf4)
{
    const unsigned int stride = gridDim.x * 256u;
    unsigned int f = blockIdx.x * 256u + threadIdx.x;
    #pragma unroll 4
    for (int it = 0; it < 4; ++it, f += stride) {
        if (f < nf4) {
            unsigned int elem = f << 2;                 // source element offset
            unsigned int rg   = elem >> 10;             // row
            unsigned int rem  = elem & 1023u;
            unsigned int g    = rem >> 5;               // 32-elem group
            unsigned int c    = (rem >> 3) & 3u;        // source chunk in group
            unsigned int half = (rem >> 2) & 1u;        // float4 within chunk
            unsigned int p    = ((rg & 2047u) >> 1) & 3u;
            float4 v = reinterpret_cast<const float4*>(keys)[f];
            uint2 w;
            w.x = f2bf2(v.x, v.y);
            w.y = f2bf2(v.z, v.w);
            unsigned int dst = rg*1024u + g*32u + ((c ^ p) << 3) + (half << 2);
            *reinterpret_cast<uint2*>(kb + dst) = w;
        }
    }
}

// ---- K3: score GEMM 128(s) x 256(h) tile, both operands via global_load_lds ----
// LDS rows 64B (32 bf16), 16B chunks XOR-swizzled: slot = chunk ^ ((row>>1)&3).
// A: kb16 already stores the permutation -> linear gld16 (2 instrs/K-step).
// B: uat plain [h][d]; permutation applied via per-lane source offset.
//    (c*16+srow >>1)&3 == (srow>>1)&3 since c*16 is 0 mod 8 -> formula holds
//    for all 16 chunk-groups.
// Frag reads (proven, 0 conflicts): base + row*32 + ((quad^((row>>1)&3))*8).
// Double-buffered, ONE barrier per K-step; per wave output 64(m) x 128(n),
// acc[4][8], 32 MFMA per thread-K-step.
// Epilogue: atomicAdd h-tile partial scores into score[32][2048].
__global__ __launch_bounds__(256) void score_gemm_fast(
    const unsigned short* __restrict__ kb16,  // [nb][2048][1024] bf16 permuted
    const unsigned short* __restrict__ uat,   // [1024][1024] bf16 [h][d]
    const float* __restrict__ qws,            // [32][1024]
    const float* __restrict__ Va,             // [1024]
    float* __restrict__ score,                // [32][2048] (pre-zeroed)
    int b0)                                   // batch offset of this chunk
{
    __shared__ unsigned short aS[2][128*32];  // 16KB
    __shared__ unsigned short bS[2][256*32];  // 32KB
    const int tid = threadIdx.x;
    const int bz = blockIdx.z;                 // local batch
    const int b = b0 + bz;                     // global batch
    const int s0 = blockIdx.x * 128;
    const int h0 = blockIdx.y * 256;
    const int lane = tid & 63, wave = tid >> 6;
    const int quad = lane >> 4, l15 = lane & 15;
    const int wm = (wave & 1) * 64, wn = (wave >> 1) * 128;

    // B-staging source (runtime-permuted, proven)
    const int srow = lane >> 2;
    const int schunk = (lane & 3) ^ ((srow >> 1) & 3);
    const unsigned short* ubase = uat + (size_t)h0*1024;
    size_t boff[4];
    #pragma unroll
    for (int u = 0; u < 4; u++) {
        int cg = wave*4 + u;                  // chunk-group 0..15 (16 rows each)
        boff[u] = (size_t)(cg*16 + srow)*1024 + schunk*8;
    }

    // A-staging source (baked-permuted, linear)
    const unsigned short* kA = kb16 + (size_t)(bz*2048 + s0)*1024;
    const size_t aoff0 = (size_t)(tid >> 2)*1024 + (size_t)(tid & 3)*8;
    const size_t aoff1 = (size_t)(64 + (tid >> 2))*1024 + (size_t)(tid & 3)*8;

    floatx4 acc[4][8];
    #pragma unroll
    for (int i = 0; i < 4; i++)
        #pragma unroll
        for (int j = 0; j < 8; j++) acc[i][j] = (floatx4)0.0f;

    // ---- prologue: stage tile 0 into buffer 0 ----
    gld16(kA + aoff0, aS[0] + wave*512);
    gld16(kA + aoff1, aS[0] + 2048 + wave*512);
    #pragma unroll
    for (int u = 0; u < 4; u++)
        gld16(ubase + boff[u], bS[0] + (wave*4 + u)*512);
    __syncthreads();

    int cur = 0;
    for (int kt = 0; kt < 31; ++kt) {
        const int nxt = cur ^ 1;
        const int k1 = (kt + 1) << 5;

        // prefetch tile kt+1 into idle buffer (6 async instrs, no VGPR traffic)
        gld16(kA + aoff0 + k1, aS[nxt] + wave*512);
        gld16(kA + aoff1 + k1, aS[nxt] + 2048 + wave*512);
        #pragma unroll
        for (int u = 0; u < 4; u++)
            gld16(ubase + boff[u] + k1, bS[nxt] + (wave*4 + u)*512);

        // compute tile kt from buf cur
        short8 af[4], bf8[8];
        #pragma unroll
        for (int i = 0; i < 4; i++) {
            int row = wm + 16*i + l15;
            af[i] = *reinterpret_cast<const short8*>(aS[cur] + row*32 + ((quad ^ ((row>>1)&3)) * 8));
        }
        #pragma unroll
        for (int j = 0; j < 8; j++) {
            int row = wn + 16*j + l15;
            bf8[j] = *reinterpret_cast<const short8*>(bS[cur] + row*32 + ((quad ^ ((row>>1)&3)) * 8));
        }
        #pragma unroll
        for (int i = 0; i < 4; i++)
            #pragma unroll
            for (int j = 0; j < 8; j++)
                acc[i][j] = __builtin_amdgcn_mfma_f32_16x16x32_bf16(af[i], bf8[j], acc[i][j], 0, 0, 0);

        __syncthreads();   // drains prefetch vmcnt + frag lgkm; one barrier/K-step
        cur = nxt;
    }

    // ---- last tile: compute only ----
    {
        short8 af[4], bf8[8];
        #pragma unroll
        for (int i = 0; i < 4; i++) {
            int row = wm + 16*i + l15;
            af[i] = *reinterpret_cast<const short8*>(aS[cur] + row*32 + ((quad ^ ((row>>1)&3)) * 8));
        }
        #pragma unroll
        for (int j = 0; j < 8; j++) {
            int row = wn + 16*j + l15;
            bf8[j] = *reinterpret_cast<const short8*>(bS[cur] + row*32 + ((quad ^ ((row>>1)&3)) * 8));
        }
        #pragma unroll
        for (int i = 0; i < 4; i++)
            #pragma unroll
            for (int j = 0; j < 8; j++)
                acc[i][j] = __builtin_amdgcn_mfma_f32_16x16x32_bf16(af[i], bf8[j], acc[i][j], 0, 0, 0);
    }

    // epilogue: p[s] = sum_n Va[n]*tanh(q[n]+k[s,n]); C-layout: n=lane&15, m=quad*4+reg
    float qv[8], vav[8];
    #pragma unroll
    for (int j = 0; j < 8; j++) {
        int n = h0 + wn + 16*j + l15;
        qv[j]  = qws[b*1024 + n];
        vav[j] = Va[n];
    }
    #pragma unroll
    for (int i = 0; i < 4; i++) {
        #pragma unroll
        for (int r = 0; r < 4; r++) {
            float p = 0.f;
            #pragma unroll
            for (int j = 0; j < 8; j++) {
                float x = qv[j] + acc[i][j][r];
                float e = __expf(2.f * x);                       // tanh = 1 - 2/(e^{2x}+1)
                float t = 1.f - 2.f * __builtin_amdgcn_rcpf(e + 1.f);
                p += vav[j] * t;
            }
            #pragma unroll
            for (int off = 1; off < 16; off <<= 1) p += __shfl_xor(p, off, 64);
            if (l15 == 0) {
                int m = wm + 16*i + quad*4 + r;
                atomicAdd(score + (size_t)b*2048 + s0 + m, p);
            }
        }
    }
}

// ---- K4: softmax over s per batch (single-pass; score pre-reduced) ----
__global__ __launch_bounds__(256) void softmax_k(const float* __restrict__ score,
                                                 float* __restrict__ out_w)
{
    const int tid = threadIdx.x;
    const int b = blockIdx.x;
    __shared__ float wred[4], wred2[4];
    float sc[8];
    float mx = -3.0e38f;
    #pragma unroll
    for (int i = 0; i < 8; i++) {
        sc[i] = score[(size_t)b*2048 + tid + 256*i];
        mx = fmaxf(mx, sc[i]);
    }
    #pragma unroll
    for (int off = 32; off >= 1; off >>= 1) mx = fmaxf(mx, __shfl_xor(mx, off, 64));
    if ((tid & 63) == 0) wred[tid >> 6] = mx;
    __syncthreads();
    mx = fmaxf(fmaxf(wred[0], wred[1]), fmaxf(wred[2], wred[3]));
    float e[8]; float lsum = 0.f;
    #pragma unroll
    for (int i = 0; i < 8; i++) { e[i] = __expf(sc[i] - mx); lsum += e[i]; }
    #pragma unroll
    for (int off = 32; off >= 1; off >>= 1) lsum += __shfl_xor(lsum, off, 64);
    if ((tid & 63) == 0) wred2[tid >> 6] = lsum;
    __syncthreads();
    float inv = 1.0f / (wred2[0] + wred2[1] + wred2[2] + wred2[3]);
    #pragma unroll
    for (int i = 0; i < 8; i++) out_w[b*2048 + tid + 256*i] = e[i] * inv;
}

// ---- K5: context accumulated directly into out_ctx via atomics ----
__global__ __launch_bounds__(256) void ctx_k(const float* __restrict__ keys,
                                             const float* __restrict__ w,
                                             float* __restrict__ out_ctx, int sper)
{
    const int tid = threadIdx.x;
    const int b = blockIdx.x, sc = blockIdx.y;
    const float4* k4 = reinterpret_cast<const float4*>(keys) + (size_t)(b*2048 + sc*sper)*256;
    const float* wp = w + b*2048 + sc*sper;
    float4 a; a.x = a.y = a.z = a.w = 0.f;
    #pragma unroll 4
    for (int s = 0; s < sper; s++) {
        float wv = wp[s];
        float4 kv = k4[(size_t)s*256 + tid];
        a.x += wv*kv.x; a.y += wv*kv.y; a.z += wv*kv.z; a.w += wv*kv.w;
    }
    float* o = out_ctx + (size_t)b*1024 + tid*4;
    atomicAdd(o + 0, a.x);
    atomicAdd(o + 1, a.y);
    atomicAdd(o + 2, a.z);
    atomicAdd(o + 3, a.w);
}

extern "C" void kernel_launch(void* const* d_in, const int* in_sizes, int n_in,
                              void* d_out, int out_size, void* d_ws, size_t ws_size,
                              hipStream_t stream)
{
    const float* query = (const float*)d_in[0];
    const float* keys  = (const float*)d_in[1];
    const float* Wa_w  = (const float*)d_in[2];
    const float* Wa_b  = (const float*)d_in[3];
    const float* Ua_w  = (const float*)d_in[4];
    const float* Ua_b  = (const float*)d_in[5];
    const float* Va_w  = (const float*)d_in[6];
    // d_in[7] (Va_b) is a uniform shift on scores -> softmax-invariant; unused.

    char* ws = (char*)d_ws;
    float*          qws     = (float*)(ws);                       // 128 KiB
    unsigned short* uat     = (unsigned short*)(ws + (131072));   // 2 MiB
    float*          score   = (float*)(ws + (131072 + 2097152));  // 256 KiB (4M region)
    const size_t BASE = 131072 + 2097152 + 4194304 + 2097152;     // 8.52 MiB
    unsigned short* kb16 = (unsigned short*)(ws + BASE);

    // pick largest batch-chunk whose kb16 fits the remaining workspace
    size_t avail = (ws_size > BASE) ? (ws_size - BASE) : 0;
    int nb = 32;
    while (nb > 1 && (size_t)nb * 2048 * 1024 * 2 > avail) nb >>= 1;

    float* out_ctx = (float*)d_out;          // [32*1024]
    float* out_w   = out_ctx + 32*1024;      // [32*2048]

    hipMemsetAsync(score, 0, 32*2048*sizeof(float), stream);
    hipMemsetAsync(out_ctx, 0, 32*1024*sizeof(float), stream);
    qproj_k<<<dim3(32, 16), 256, 0, stream>>>(query, Wa_w, Wa_b, Ua_b, qws);
    uat_k  <<<dim3(16, 16), 256, 0, stream>>>(Ua_w, uat);
    for (int b0 = 0; b0 < 32; b0 += nb) {
        unsigned int nf4 = (unsigned int)nb * 2048u * 256u;
        unsigned int nthr = (nf4 + 3u) / 4u;
        unsigned int nblk = (nthr + 255u) / 256u;
        kb16_k<<<dim3(nblk), 256, 0, stream>>>(keys + (size_t)b0*2048*1024, kb16, nf4);
        score_gemm_fast<<<dim3(16, 4, nb), 256, 0, stream>>>(kb16, uat, qws, Va_w, score, b0);
    }
    softmax_k<<<dim3(32),      256, 0, stream>>>(score, out_w);
    ctx_k    <<<dim3(32, 16),  256, 0, stream>>>(keys, out_w, out_ctx, 128);
}